// Round 17
// baseline (422.362 us; speedup 1.0000x reference)
//
#include <hip/hip_runtime.h>

typedef short s8v __attribute__((ext_vector_type(8)));
typedef short s4v __attribute__((ext_vector_type(4)));
typedef float f4v __attribute__((ext_vector_type(4)));

#define DEV __device__ __forceinline__

DEV short f2bs(float f){
  unsigned int u = __float_as_uint(f);
  u += 0x7fffu + ((u >> 16) & 1u);
  return (short)(u >> 16);
}
DEV float b2f(short s){
  return __uint_as_float(((unsigned int)(unsigned short)s) << 16);
}
DEV float lrelu(float x){ return x >= 0.f ? x : 0.01f*x; }
DEV unsigned pk2(float a, float b){
  return (unsigned)(unsigned short)f2bs(a) | ((unsigned)(unsigned short)f2bs(b) << 16);
}

// ---------------- K0: weight prep ----------------
__global__ __launch_bounds__(256) void k0_prep(
    const float* __restrict__ w1, const float* __restrict__ w2,
    const float* __restrict__ w3, const float* __restrict__ rw2,
    const float* __restrict__ wq, const float* __restrict__ wk,
    const float* __restrict__ wv, const float* __restrict__ wo,
    char* __restrict__ wreg)
{
  int idx = blockIdx.x*256 + threadIdx.x;
  short* w1b = (short*)(wreg);
  short* w2b = (short*)(wreg + 3456);
  short* w3b = (short*)(wreg + 40320);
  short* rw2b = (short*)(wreg + 114048);
  short* wkb  = (short*)(wreg + 130432);
  short* wvb  = (short*)(wreg + 138624);
  short* wob  = (short*)(wreg + 146816);
  if (idx < 1024){
    int e = idx & 7, l = (idx >> 3) & 63, m = idx >> 9;
    int k = (l >> 4)*8 + e;
    int cout = m*16 + (l & 15);
    w1b[idx] = (k < 27) ? f2bs(w1[cout*27 + k]) : (short)0;
  } else if (idx < 19456){
    int j = idx - 1024;
    int kk = j / 2048, c = (j >> 5) & 63, ci = j & 31;
    w2b[j] = f2bs(w2[c*288 + ci*9 + kk]);
  } else if (idx < 56320){
    int j = idx - 19456;
    int kk = j / 4096, c = (j >> 6) & 63, ci = j & 63;
    w3b[j] = f2bs(w3[c*576 + ci*9 + kk]);
  } else if (idx < 60416){
    int j = idx - 56320; rw2b[j] = f2bs(rw2[j]);
  } else if (idx < 64512){
    // wqrb written by k0b
  } else if (idx < 68608){
    int j = idx - 64512; wkb[j] = f2bs(wk[j]);
  } else if (idx < 72704){
    int j = idx - 68608; wvb[j] = f2bs(wv[j]);
  } else if (idx < 76800){
    int j = idx - 72704; wob[j] = f2bs(wo[j]);
  }
}

// ---------------- K0b: fold wq*rw2 -> wqrb (bf16), wq@rb2+bq -> bqr (f32) ----------------
__global__ __launch_bounds__(256) void k0b_fold(
    const float* __restrict__ wq, const float* __restrict__ rw2,
    const float* __restrict__ rb2, const float* __restrict__ bq,
    char* __restrict__ wreg)
{
  short* wqrb = (short*)(wreg + 122240);
  float* bqr  = (float*)(wreg + 155008);
  int tid = threadIdx.x;
  int i = tid >> 2, k0 = (tid & 3)*16;
  #pragma unroll
  for (int kk=0; kk<16; kk++){
    int k = k0 + kk;
    float s = 0.f;
    #pragma unroll
    for (int j=0; j<64; j++) s += wq[i*64+j]*rw2[j*64+k];
    wqrb[i*64+k] = f2bs(s);
  }
  if (tid < 64){
    float s = bq[tid];
    #pragma unroll
    for (int j=0; j<64; j++) s += wq[tid*64+j]*rb2[j];
    bqr[tid] = s;
  }
}

// ---------------- KC12: fused conv1+conv2 (unchanged) ----------------
__global__ __launch_bounds__(256) void kc12(
    const float* __restrict__ vt, short* __restrict__ c2,
    const short* __restrict__ w1b, const float* __restrict__ b1,
    const short* __restrict__ w2b, const float* __restrict__ b2, int v0)
{
  __shared__ short srcT[3108];
  __shared__ short rb[4][2880];
  const int tid = threadIdx.x;
  const int l = tid & 63, wid = tid >> 6;
  const int p = l & 15, g = l >> 4;
  const int OXB = blockIdx.x*64, OYB = blockIdx.y*2;
  const float* src = vt + (size_t)(v0 + blockIdx.z)*3*512*512;

  #pragma unroll
  for (int it=0; it<13; it++){
    int idx = it*256 + tid;
    if (idx < 3108){
      int ci = idx/1036, rem = idx - ci*1036;
      int row = rem/148, col = rem - row*148;
      int gr = min(max(2*OYB - 2 + row, 0), 511);
      int gc = min(max(2*OXB - 2 + col, 0), 511);
      srcT[idx] = f2bs(src[((size_t)ci*512 + gr)*512 + gc]);
    }
  }

  int boffB[8];
  #pragma unroll
  for (int e=0;e<8;e++){
    int k = g*8 + e;
    int ci = (k*57) >> 9;
    int r9 = k - ci*9;
    int dy = (r9*11) >> 5;
    int dx = r9 - dy*3;
    boffB[e] = (k < 27) ? (ci*1036 + dy*148 + dx) : 0;
  }
  s8v af0 = *(const s8v*)(w1b + l*8);
  s8v af1 = *(const s8v*)(w1b + 512 + l*8);
  f4v cb0 = *(const f4v*)(b1 + g*4);
  f4v cb1 = *(const f4v*)(b1 + 16 + g*4);

  const int dlt = wid >> 1, h = wid & 1;
  const int oy = OYB + dlt;
  const int ox0 = OXB + h*32;
  const int Cw0 = 2*ox0 - 1;
  short* myrb = rb[wid];
  const f4v FZ = {0.f,0.f,0.f,0.f};
  f4v acc[2][4];
  #pragma unroll
  for (int s2=0;s2<2;s2++)
    #pragma unroll
    for (int m=0;m<4;m++) acc[s2][m] = FZ;

  __syncthreads();

  #pragma unroll
  for (int ky=0; ky<3; ky++){
    const int R = min(max(2*oy + ky - 1, 0), 511);
    const int trb = R - 2*OYB + 1;
    const int sbase = trb*148 + 64*h + p;

    #pragma unroll
    for (int s=0; s<5; s++){
      s8v bf;
      #pragma unroll
      for (int e=0;e<8;e++) bf[e] = srcT[boffB[e] + sbase + s*16];
      f4v d0 = __builtin_amdgcn_mfma_f32_16x16x32_bf16(af0, bf, FZ, 0,0,0);
      f4v d1 = __builtin_amdgcn_mfma_f32_16x16x32_bf16(af1, bf, FZ, 0,0,0);
      int wcol = s*16 + p;
      uint2 wa = { pk2(lrelu(d0[0]+cb0[0]), lrelu(d0[1]+cb0[1])),
                   pk2(lrelu(d0[2]+cb0[2]), lrelu(d0[3]+cb0[3])) };
      *(uint2*)(myrb + wcol*36 + g*4) = wa;
      uint2 wb2 = { pk2(lrelu(d1[0]+cb1[0]), lrelu(d1[1]+cb1[1])),
                    pk2(lrelu(d1[2]+cb1[2]), lrelu(d1[3]+cb1[3])) };
      *(uint2*)(myrb + wcol*36 + 16 + g*4) = wb2;
    }

    #pragma unroll
    for (int s2=0; s2<2; s2++){
      const int locox = s2*16 + p;
      #pragma unroll
      for (int kx=0; kx<3; kx++){
        int raw = Cw0 + 2*locox + kx;
        int ri = max(raw, 0) - Cw0;
        uint2 lo2 = *(const uint2*)(myrb + ri*36 + g*8);
        uint2 hi2 = *(const uint2*)(myrb + ri*36 + g*8 + 4);
        uint4 t4 = {lo2.x, lo2.y, hi2.x, hi2.y};
        s8v bf2 = __builtin_bit_cast(s8v, t4);
        #pragma unroll
        for (int m=0;m<4;m++){
          s8v afr = *(const s8v*)(w2b + ((ky*3+kx)*64 + m*16 + p)*32 + g*8);
          acc[s2][m] = __builtin_amdgcn_mfma_f32_16x16x32_bf16(afr, bf2, acc[s2][m], 0,0,0);
        }
      }
    }
  }

  #pragma unroll
  for (int s2=0; s2<2; s2++){
    short* o = c2 + (((size_t)blockIdx.z*256 + oy)*256 + ox0 + s2*16 + p)*64;
    #pragma unroll
    for (int m=0;m<4;m++){
      f4v bb = *(const f4v*)(b2 + m*16 + g*4);
      s4v pk;
      #pragma unroll
      for (int r=0;r<4;r++) pk[r] = f2bs(lrelu(acc[s2][m][r] + bb[r]));
      *(s4v*)(o + m*16 + g*4) = pk;
    }
  }
}

// ---------------- conv3: implicit-GEMM MFMA, stride 2 ----------------
template<int CIN, int TILES>
__global__ __launch_bounds__(256) void conv_mfma(
    const short* __restrict__ src0, short* __restrict__ dst,
    const short* __restrict__ wb, const float* __restrict__ bias,
    int IH, int IW, int OW, int dstV0)
{
  const int l = threadIdx.x & 63, w = threadIdx.x >> 6;
  const int p = l & 15, g = l >> 4;
  const int ox0 = blockIdx.x*(64*TILES) + w*(16*TILES) + p;
  const int oy = blockIdx.y;
  const short* src = src0 + (size_t)blockIdx.z*IH*IW*CIN;
  const f4v FZ = {0.f,0.f,0.f,0.f};
  f4v acc[TILES][4];
  #pragma unroll
  for (int tl=0;tl<TILES;tl++)
    #pragma unroll
    for (int m=0;m<4;m++) acc[tl][m] = FZ;
  #pragma unroll
  for (int ky=0;ky<3;ky++){
    int iy = min(max(2*oy+ky-1, 0), IH-1);
    #pragma unroll
    for (int kx=0;kx<3;kx++){
      #pragma unroll
      for (int ch=0; ch<CIN/32; ch++){
        s8v bfrag[TILES];
        #pragma unroll
        for (int tl=0;tl<TILES;tl++){
          int ix = min(max(2*(ox0 + 16*tl)+kx-1, 0), IW-1);
          bfrag[tl] = *(const s8v*)(src + ((size_t)iy*IW + ix)*CIN + ch*32 + g*8);
        }
        #pragma unroll
        for (int m=0;m<4;m++){
          s8v afrag = *(const s8v*)(wb + ((ky*3+kx)*64 + m*16 + p)*CIN + ch*32 + g*8);
          #pragma unroll
          for (int tl=0;tl<TILES;tl++)
            acc[tl][m] = __builtin_amdgcn_mfma_f32_16x16x32_bf16(afrag, bfrag[tl], acc[tl][m], 0,0,0);
        }
      }
    }
  }
  const int OH = gridDim.y;
  #pragma unroll
  for (int tl=0;tl<TILES;tl++){
    short* o = dst + (((size_t)(dstV0 + blockIdx.z)*OH + oy)*OW + ox0 + 16*tl)*64;
    #pragma unroll
    for (int m=0;m<4;m++){
      f4v bb = *(const f4v*)(bias + m*16 + g*4);
      s4v pk;
      #pragma unroll
      for (int r=0;r<4;r++) pk[r] = f2bs(lrelu(acc[tl][m][r] + bb[r]));
      *(s4v*)(o + m*16 + g*4) = pk;
    }
  }
}

// ---------------- K45: fused gather + rayMLP + MHA, register-direct (R16) ----------------
#define AFRG(W) (*(const s8v*)((W) + (m*16 + p)*64 + kc*32 + g*8))

__global__ __launch_bounds__(256) void k45_fused(
    const short* __restrict__ nts, const float* __restrict__ uvi,
    const float* __restrict__ raydir,
    const float* __restrict__ rw1, const float* __restrict__ rb1,
    const short* __restrict__ wqrb, const float* __restrict__ bqr,
    const short* __restrict__ wkb, const float* __restrict__ bk,
    const short* __restrict__ wvb, const float* __restrict__ bv,
    const short* __restrict__ wob, const float* __restrict__ bo,
    float* __restrict__ outFused, float* __restrict__ outFeats)
{
  __shared__ unsigned rlds[4][576];           // relayout scratch, 9216 B
  const int tid = threadIdx.x;
  const int l = tid & 63, wid = tid >> 6;
  const int p = l & 15, g = l >> 4;
  const int pt = blockIdx.x*64 + wid*16 + p;
  const f4v FZ = {0.f,0.f,0.f,0.f};

  const float* up = uvi + (size_t)pt*9;
  float uu[3], vv[3];
  int vidv[3];
  #pragma unroll
  for (int t=0;t<3;t++){
    uu[t] = up[t*3+0]; vv[t] = up[t*3+1]; vidv[t] = (int)up[t*3+2];
  }

  s8v fb[3][2];
  #pragma unroll
  for (int t=0;t<3;t++){
    float xf = uu[t]*127.f, yf = vv[t]*127.f;
    int x0 = min(max((int)floorf(xf), 0), 126);
    int y0 = min(max((int)floorf(yf), 0), 126);
    float wx = xf - (float)x0, wy = yf - (float)y0;
    const short* cb = nts + ((size_t)((vidv[t]*128 + y0)*128 + x0))*64 + g*8;
    #pragma unroll
    for (int kc=0;kc<2;kc++){
      const short* bp = cb + kc*32;
      s8v c00 = *(const s8v*)(bp);
      s8v c01 = *(const s8v*)(bp + 64);
      s8v c10 = *(const s8v*)(bp + 8192);
      s8v c11 = *(const s8v*)(bp + 8192 + 64);
      f4v v0, v1;
      s8v pk;
      #pragma unroll
      for (int e=0;e<8;e++){
        float a = b2f(c00[e]); a += wx*(b2f(c01[e]) - a);
        float b = b2f(c10[e]); b += wx*(b2f(c11[e]) - b);
        float val = a + wy*(b - a);
        if (e < 4) v0[e] = val; else v1[e-4] = val;
        pk[e] = f2bs(val);
      }
      float* op = outFeats + ((size_t)pt*3 + t)*64 + kc*32 + g*8;
      *(f4v*)op = v0;
      *(f4v*)(op+4) = v1;
      fb[t][kc] = pk;
    }
  }

  float rd0 = raydir[(size_t)pt*3+0];
  float rd1 = raydir[(size_t)pt*3+1];
  float rd2 = raydir[(size_t)pt*3+2];
  s8v xb[2];
  #pragma unroll
  for (int kc=0;kc<2;kc++){
    s8v tmp;
    #pragma unroll
    for (int e=0;e<8;e++){
      int j = kc*32 + g*8 + e;
      float hv = fmaxf(rb1[j] + rw1[j*3]*rd0 + rw1[j*3+1]*rd1 + rw1[j*3+2]*rd2, 0.f);
      tmp[e] = f2bs(hv);
    }
    xb[kc] = tmp;
  }

  f4v acc[4];
  #pragma unroll
  for (int m=0;m<4;m++) acc[m] = FZ;
  #pragma unroll
  for (int kc=0;kc<2;kc++){
    #pragma unroll
    for (int m=0;m<4;m++)
      acc[m] = __builtin_amdgcn_mfma_f32_16x16x32_bf16(AFRG(wqrb), xb[kc], acc[m], 0,0,0);
  }
  float qh[4][4];
  #pragma unroll
  for (int m=0;m<4;m++){
    f4v bb = *(const f4v*)(bqr + m*16 + g*4);
    #pragma unroll
    for (int r=0;r<4;r++) qh[m][r] = acc[m][r] + bb[r];
  }

  s8v wkf[2][4];
  #pragma unroll
  for (int kc=0;kc<2;kc++)
    #pragma unroll
    for (int m=0;m<4;m++)
      wkf[kc][m] = AFRG(wkb);

  float sc[3][4];
  #pragma unroll
  for (int t=0;t<3;t++){
    f4v ka[4];
    #pragma unroll
    for (int m=0;m<4;m++) ka[m] = FZ;
    #pragma unroll
    for (int kc=0;kc<2;kc++){
      #pragma unroll
      for (int m=0;m<4;m++)
        ka[m] = __builtin_amdgcn_mfma_f32_16x16x32_bf16(wkf[kc][m], fb[t][kc], ka[m], 0,0,0);
    }
    #pragma unroll
    for (int m=0;m<4;m++){
      f4v bb = *(const f4v*)(bk + m*16 + g*4);
      float part = 0.f;
      #pragma unroll
      for (int r=0;r<4;r++) part += qh[m][r]*(ka[m][r] + bb[r]);
      part += __shfl_xor(part, 16, 64);
      part += __shfl_xor(part, 32, 64);
      sc[t][m] = part*0.25f;
    }
  }

  #pragma unroll
  for (int m=0;m<4;m++){
    float mx = fmaxf(fmaxf(sc[0][m], sc[1][m]), sc[2][m]);
    float e0 = __expf(sc[0][m]-mx);
    float e1 = __expf(sc[1][m]-mx);
    float e2 = __expf(sc[2][m]-mx);
    float inv = 1.f/(e0+e1+e2);
    sc[0][m] = e0*inv; sc[1][m] = e1*inv; sc[2][m] = e2*inv;
  }

  s8v wvf[2][4];
  #pragma unroll
  for (int kc=0;kc<2;kc++)
    #pragma unroll
    for (int m=0;m<4;m++)
      wvf[kc][m] = AFRG(wvb);

  float o[4][4];
  #pragma unroll
  for (int m=0;m<4;m++)
    #pragma unroll
    for (int r=0;r<4;r++) o[m][r] = 0.f;
  #pragma unroll
  for (int t=0;t<3;t++){
    f4v va[4];
    #pragma unroll
    for (int m=0;m<4;m++) va[m] = FZ;
    #pragma unroll
    for (int kc=0;kc<2;kc++){
      #pragma unroll
      for (int m=0;m<4;m++)
        va[m] = __builtin_amdgcn_mfma_f32_16x16x32_bf16(wvf[kc][m], fb[t][kc], va[m], 0,0,0);
    }
    #pragma unroll
    for (int m=0;m<4;m++)
      #pragma unroll
      for (int r=0;r<4;r++) o[m][r] += sc[t][m]*va[m][r];
  }
  #pragma unroll
  for (int m=0;m<4;m++){
    f4v bb = *(const f4v*)(bv + m*16 + g*4);
    #pragma unroll
    for (int r=0;r<4;r++) o[m][r] += bb[r];
  }

  {
    unsigned* rl = rlds[wid];
    #pragma unroll
    for (int m=0;m<4;m++){
      unsigned lo = pk2(o[m][0], o[m][1]);
      unsigned hi = pk2(o[m][2], o[m][3]);
      rl[p*36 + m*8 + g*2] = lo;
      rl[p*36 + m*8 + g*2 + 1] = hi;
    }
    xb[0] = __builtin_bit_cast(s8v, *(uint4*)(rl + p*36 + g*4));
    xb[1] = __builtin_bit_cast(s8v, *(uint4*)(rl + p*36 + 16 + g*4));
  }

  #pragma unroll
  for (int m=0;m<4;m++) acc[m] = FZ;
  #pragma unroll
  for (int kc=0;kc<2;kc++){
    #pragma unroll
    for (int m=0;m<4;m++)
      acc[m] = __builtin_amdgcn_mfma_f32_16x16x32_bf16(AFRG(wob), xb[kc], acc[m], 0,0,0);
  }
  #pragma unroll
  for (int m=0;m<4;m++){
    f4v bb = *(const f4v*)(bo + m*16 + g*4);
    f4v res;
    #pragma unroll
    for (int r=0;r<4;r++) res[r] = acc[m][r] + bb[r];
    *(f4v*)(outFused + (size_t)pt*64 + m*16 + g*4) = res;
  }
}

extern "C" void kernel_launch(void* const* d_in, const int* in_sizes, int n_in,
                              void* d_out, int out_size, void* d_ws, size_t ws_size,
                              hipStream_t stream)
{
  const float* view_tex = (const float*)d_in[0];
  const float* uvi    = (const float*)d_in[1];
  const float* raydir = (const float*)d_in[2];
  const float* w1 = (const float*)d_in[3];
  const float* b1 = (const float*)d_in[4];
  const float* w2 = (const float*)d_in[5];
  const float* b2 = (const float*)d_in[6];
  const float* w3 = (const float*)d_in[7];
  const float* b3 = (const float*)d_in[8];
  const float* rw1 = (const float*)d_in[9];
  const float* rb1 = (const float*)d_in[10];
  const float* rw2 = (const float*)d_in[11];
  const float* rb2 = (const float*)d_in[12];
  const float* wq = (const float*)d_in[13];
  const float* bq = (const float*)d_in[14];
  const float* wk = (const float*)d_in[15];
  const float* bk = (const float*)d_in[16];
  const float* wv = (const float*)d_in[17];
  const float* bv = (const float*)d_in[18];
  const float* wo = (const float*)d_in[19];
  const float* bo = (const float*)d_in[20];
  float* out = (float*)d_out;

  const int V = in_sizes[0] / (3*512*512);     // 8
  const int B = in_sizes[1] / 9;               // 262144
  const size_t FEATS_OFF = (size_t)B*64;

  const size_t C2F  = (size_t)V*256*256*64*2;
  const size_t C2V  = (size_t)256*256*64*2;
  const size_t NTSB = (size_t)V*128*128*64*2;
  const size_t WREG = 262144;

  char* base = (char*)d_ws;
  bool full = (ws_size >= C2F + NTSB + WREG);

  char *c2, *ntsp, *wreg;
  if (full){
    c2 = base; ntsp = c2 + C2F; wreg = ntsp + NTSB;
  } else {
    c2 = base; ntsp = c2 + C2V; wreg = ntsp + NTSB;
  }
  short* w1b = (short*)(wreg);
  short* w2b = (short*)(wreg + 3456);
  short* w3b = (short*)(wreg + 40320);
  short* wqrb = (short*)(wreg + 122240);
  short* wkb  = (short*)(wreg + 130432);
  short* wvb  = (short*)(wreg + 138624);
  short* wob  = (short*)(wreg + 146816);
  float* bqr  = (float*)(wreg + 155008);

  k0_prep<<<dim3(300),256,0,stream>>>(w1,w2,w3,rw2,wq,wk,wv,wo,wreg);
  k0b_fold<<<dim3(1),256,0,stream>>>(wq, rw2, rb2, bq, wreg);

  if (full){
    kc12<<<dim3(4,128,V),256,0,stream>>>(view_tex,(short*)c2,w1b,b1,w2b,b2,0);
    // ATTRIBUTION PROBE: conv3 launched 3x (idempotent, serialized).
    // c3 = (total_us - 317.6) / 2.
    for (int rep=0; rep<3; rep++)
      conv_mfma<64,2><<<dim3(1,128,V),256,0,stream>>>((const short*)c2,(short*)ntsp,w3b,b3,256,256,128,0);
  } else {
    for (int v=0; v<V; v++){
      kc12<<<dim3(4,128,1),256,0,stream>>>(view_tex,(short*)c2,w1b,b1,w2b,b2,v);
      conv_mfma<64,2><<<dim3(1,128,1),256,0,stream>>>((const short*)c2,(short*)ntsp,w3b,b3,256,256,128,v);
    }
  }

  k45_fused<<<dim3(B/64),256,0,stream>>>((const short*)ntsp, uvi, raydir,
      rw1, rb1, wqrb, bqr, wkb, bk, wvb, bv, wob, bo,
      out, out + FEATS_OFF);
}

// Round 18
// 321.409 us; speedup vs baseline: 1.3141x; 1.3141x over previous
//
#include <hip/hip_runtime.h>

typedef short s8v __attribute__((ext_vector_type(8)));
typedef short s4v __attribute__((ext_vector_type(4)));
typedef float f4v __attribute__((ext_vector_type(4)));

#define DEV __device__ __forceinline__

DEV short f2bs(float f){
  unsigned int u = __float_as_uint(f);
  u += 0x7fffu + ((u >> 16) & 1u);
  return (short)(u >> 16);
}
DEV float b2f(short s){
  return __uint_as_float(((unsigned int)(unsigned short)s) << 16);
}
DEV float lrelu(float x){ return x >= 0.f ? x : 0.01f*x; }
DEV unsigned pk2(float a, float b){
  return (unsigned)(unsigned short)f2bs(a) | ((unsigned)(unsigned short)f2bs(b) << 16);
}

// ---------------- K0: weight prep ----------------
__global__ __launch_bounds__(256) void k0_prep(
    const float* __restrict__ w1, const float* __restrict__ w2,
    const float* __restrict__ w3, const float* __restrict__ rw2,
    const float* __restrict__ wq, const float* __restrict__ wk,
    const float* __restrict__ wv, const float* __restrict__ wo,
    char* __restrict__ wreg)
{
  int idx = blockIdx.x*256 + threadIdx.x;
  short* w1b = (short*)(wreg);
  short* w2b = (short*)(wreg + 3456);
  short* w3b = (short*)(wreg + 40320);
  short* rw2b = (short*)(wreg + 114048);
  short* wkb  = (short*)(wreg + 130432);
  short* wvb  = (short*)(wreg + 138624);
  short* wob  = (short*)(wreg + 146816);
  if (idx < 1024){
    int e = idx & 7, l = (idx >> 3) & 63, m = idx >> 9;
    int k = (l >> 4)*8 + e;
    int cout = m*16 + (l & 15);
    w1b[idx] = (k < 27) ? f2bs(w1[cout*27 + k]) : (short)0;
  } else if (idx < 19456){
    int j = idx - 1024;
    int kk = j / 2048, c = (j >> 5) & 63, ci = j & 31;
    w2b[j] = f2bs(w2[c*288 + ci*9 + kk]);
  } else if (idx < 56320){
    int j = idx - 19456;
    int kk = j / 4096, c = (j >> 6) & 63, ci = j & 63;
    w3b[j] = f2bs(w3[c*576 + ci*9 + kk]);
  } else if (idx < 60416){
    int j = idx - 56320; rw2b[j] = f2bs(rw2[j]);
  } else if (idx < 64512){
    // wqrb written by k0b
  } else if (idx < 68608){
    int j = idx - 64512; wkb[j] = f2bs(wk[j]);
  } else if (idx < 72704){
    int j = idx - 68608; wvb[j] = f2bs(wv[j]);
  } else if (idx < 76800){
    int j = idx - 72704; wob[j] = f2bs(wo[j]);
  }
}

// ---------------- K0b: fold wq*rw2 -> wqrb (bf16), wq@rb2+bq -> bqr (f32) ----------------
__global__ __launch_bounds__(256) void k0b_fold(
    const float* __restrict__ wq, const float* __restrict__ rw2,
    const float* __restrict__ rb2, const float* __restrict__ bq,
    char* __restrict__ wreg)
{
  short* wqrb = (short*)(wreg + 122240);
  float* bqr  = (float*)(wreg + 155008);
  int tid = threadIdx.x;
  int i = tid >> 2, k0 = (tid & 3)*16;
  #pragma unroll
  for (int kk=0; kk<16; kk++){
    int k = k0 + kk;
    float s = 0.f;
    #pragma unroll
    for (int j=0; j<64; j++) s += wq[i*64+j]*rw2[j*64+k];
    wqrb[i*64+k] = f2bs(s);
  }
  if (tid < 64){
    float s = bq[tid];
    #pragma unroll
    for (int j=0; j<64; j++) s += wq[tid*64+j]*rb2[j];
    bqr[tid] = s;
  }
}

// ---------------- KC12: fused conv1+conv2 (unchanged) ----------------
__global__ __launch_bounds__(256) void kc12(
    const float* __restrict__ vt, short* __restrict__ c2,
    const short* __restrict__ w1b, const float* __restrict__ b1,
    const short* __restrict__ w2b, const float* __restrict__ b2, int v0)
{
  __shared__ short srcT[3108];
  __shared__ short rb[4][2880];
  const int tid = threadIdx.x;
  const int l = tid & 63, wid = tid >> 6;
  const int p = l & 15, g = l >> 4;
  const int OXB = blockIdx.x*64, OYB = blockIdx.y*2;
  const float* src = vt + (size_t)(v0 + blockIdx.z)*3*512*512;

  #pragma unroll
  for (int it=0; it<13; it++){
    int idx = it*256 + tid;
    if (idx < 3108){
      int ci = idx/1036, rem = idx - ci*1036;
      int row = rem/148, col = rem - row*148;
      int gr = min(max(2*OYB - 2 + row, 0), 511);
      int gc = min(max(2*OXB - 2 + col, 0), 511);
      srcT[idx] = f2bs(src[((size_t)ci*512 + gr)*512 + gc]);
    }
  }

  int boffB[8];
  #pragma unroll
  for (int e=0;e<8;e++){
    int k = g*8 + e;
    int ci = (k*57) >> 9;
    int r9 = k - ci*9;
    int dy = (r9*11) >> 5;
    int dx = r9 - dy*3;
    boffB[e] = (k < 27) ? (ci*1036 + dy*148 + dx) : 0;
  }
  s8v af0 = *(const s8v*)(w1b + l*8);
  s8v af1 = *(const s8v*)(w1b + 512 + l*8);
  f4v cb0 = *(const f4v*)(b1 + g*4);
  f4v cb1 = *(const f4v*)(b1 + 16 + g*4);

  const int dlt = wid >> 1, h = wid & 1;
  const int oy = OYB + dlt;
  const int ox0 = OXB + h*32;
  const int Cw0 = 2*ox0 - 1;
  short* myrb = rb[wid];
  const f4v FZ = {0.f,0.f,0.f,0.f};
  f4v acc[2][4];
  #pragma unroll
  for (int s2=0;s2<2;s2++)
    #pragma unroll
    for (int m=0;m<4;m++) acc[s2][m] = FZ;

  __syncthreads();

  #pragma unroll
  for (int ky=0; ky<3; ky++){
    const int R = min(max(2*oy + ky - 1, 0), 511);
    const int trb = R - 2*OYB + 1;
    const int sbase = trb*148 + 64*h + p;

    #pragma unroll
    for (int s=0; s<5; s++){
      s8v bf;
      #pragma unroll
      for (int e=0;e<8;e++) bf[e] = srcT[boffB[e] + sbase + s*16];
      f4v d0 = __builtin_amdgcn_mfma_f32_16x16x32_bf16(af0, bf, FZ, 0,0,0);
      f4v d1 = __builtin_amdgcn_mfma_f32_16x16x32_bf16(af1, bf, FZ, 0,0,0);
      int wcol = s*16 + p;
      uint2 wa = { pk2(lrelu(d0[0]+cb0[0]), lrelu(d0[1]+cb0[1])),
                   pk2(lrelu(d0[2]+cb0[2]), lrelu(d0[3]+cb0[3])) };
      *(uint2*)(myrb + wcol*36 + g*4) = wa;
      uint2 wb2 = { pk2(lrelu(d1[0]+cb1[0]), lrelu(d1[1]+cb1[1])),
                    pk2(lrelu(d1[2]+cb1[2]), lrelu(d1[3]+cb1[3])) };
      *(uint2*)(myrb + wcol*36 + 16 + g*4) = wb2;
    }

    #pragma unroll
    for (int s2=0; s2<2; s2++){
      const int locox = s2*16 + p;
      #pragma unroll
      for (int kx=0; kx<3; kx++){
        int raw = Cw0 + 2*locox + kx;
        int ri = max(raw, 0) - Cw0;
        uint2 lo2 = *(const uint2*)(myrb + ri*36 + g*8);
        uint2 hi2 = *(const uint2*)(myrb + ri*36 + g*8 + 4);
        uint4 t4 = {lo2.x, lo2.y, hi2.x, hi2.y};
        s8v bf2 = __builtin_bit_cast(s8v, t4);
        #pragma unroll
        for (int m=0;m<4;m++){
          s8v afr = *(const s8v*)(w2b + ((ky*3+kx)*64 + m*16 + p)*32 + g*8);
          acc[s2][m] = __builtin_amdgcn_mfma_f32_16x16x32_bf16(afr, bf2, acc[s2][m], 0,0,0);
        }
      }
    }
  }

  #pragma unroll
  for (int s2=0; s2<2; s2++){
    short* o = c2 + (((size_t)blockIdx.z*256 + oy)*256 + ox0 + s2*16 + p)*64;
    #pragma unroll
    for (int m=0;m<4;m++){
      f4v bb = *(const f4v*)(b2 + m*16 + g*4);
      s4v pk;
      #pragma unroll
      for (int r=0;r<4;r++) pk[r] = f2bs(lrelu(acc[s2][m][r] + bb[r]));
      *(s4v*)(o + m*16 + g*4) = pk;
    }
  }
}

// ---------------- conv3: cout-split implicit-GEMM MFMA (grid.x = cout half) ----------------
// Block (mh, oy, v): computes couts mh*32..mh*32+31 for the full 128-px row oy.
// Halved acc (16 VGPR) + halved per-wave weight traffic -> 2x TLP for latency hiding.
template<int CIN, int TILES>
__global__ __launch_bounds__(256) void conv_mfma_ms(
    const short* __restrict__ src0, short* __restrict__ dst,
    const short* __restrict__ wb, const float* __restrict__ bias,
    int IH, int IW, int OW, int dstV0)
{
  const int l = threadIdx.x & 63, w = threadIdx.x >> 6;
  const int p = l & 15, g = l >> 4;
  const int mh = blockIdx.x;                  // cout half: m = mh*2 + mm
  const int ox0 = w*(16*TILES) + p;
  const int oy = blockIdx.y;
  const short* src = src0 + (size_t)blockIdx.z*IH*IW*CIN;
  const f4v FZ = {0.f,0.f,0.f,0.f};
  f4v acc[TILES][2];
  #pragma unroll
  for (int tl=0;tl<TILES;tl++)
    #pragma unroll
    for (int mm=0;mm<2;mm++) acc[tl][mm] = FZ;
  #pragma unroll
  for (int ky=0;ky<3;ky++){
    int iy = min(max(2*oy+ky-1, 0), IH-1);
    #pragma unroll
    for (int kx=0;kx<3;kx++){
      #pragma unroll
      for (int ch=0; ch<CIN/32; ch++){
        s8v bfrag[TILES];
        #pragma unroll
        for (int tl=0;tl<TILES;tl++){
          int ix = min(max(2*(ox0 + 16*tl)+kx-1, 0), IW-1);
          bfrag[tl] = *(const s8v*)(src + ((size_t)iy*IW + ix)*CIN + ch*32 + g*8);
        }
        #pragma unroll
        for (int mm=0;mm<2;mm++){
          s8v afrag = *(const s8v*)(wb + ((ky*3+kx)*64 + (mh*2+mm)*16 + p)*CIN + ch*32 + g*8);
          #pragma unroll
          for (int tl=0;tl<TILES;tl++)
            acc[tl][mm] = __builtin_amdgcn_mfma_f32_16x16x32_bf16(afrag, bfrag[tl], acc[tl][mm], 0,0,0);
        }
      }
    }
  }
  const int OH = gridDim.y;
  #pragma unroll
  for (int tl=0;tl<TILES;tl++){
    short* o = dst + (((size_t)(dstV0 + blockIdx.z)*OH + oy)*OW + ox0 + 16*tl)*64;
    #pragma unroll
    for (int mm=0;mm<2;mm++){
      int m = mh*2 + mm;
      f4v bb = *(const f4v*)(bias + m*16 + g*4);
      s4v pk;
      #pragma unroll
      for (int r=0;r<4;r++) pk[r] = f2bs(lrelu(acc[tl][mm][r] + bb[r]));
      *(s4v*)(o + m*16 + g*4) = pk;
    }
  }
}

// ---------------- K45: fused gather + rayMLP + MHA (R11 structure, best measured) ----------------
#define AFRG(W) (*(const s8v*)((W) + (m*16 + p)*64 + kc*32 + g*8))

__global__ __launch_bounds__(256) void k45_fused(
    const short* __restrict__ nts, const float* __restrict__ uvi,
    const float* __restrict__ raydir,
    const float* __restrict__ rw1, const float* __restrict__ rb1,
    const short* __restrict__ wqrb, const float* __restrict__ bqr,
    const short* __restrict__ wkb, const float* __restrict__ bk,
    const short* __restrict__ wvb, const float* __restrict__ bv,
    const short* __restrict__ wob, const float* __restrict__ bo,
    float* __restrict__ outFused, float* __restrict__ outFeats)
{
  __shared__ short lds_fb[64*3*72];           // 27648 B
  const int tid = threadIdx.x;
  const int l = tid & 63, wid = tid >> 6;
  const int p = l & 15, g = l >> 4;
  const int pt0 = blockIdx.x*64;
  const f4v FZ = {0.f,0.f,0.f,0.f};

  // ---- phase 1: gather 64 pts x 3 tok x 64 ch (8-ch chunks) ----
  #pragma unroll
  for (int i=0; i<6; i++){
    int ck = i*256 + tid;                     // [0,1536)
    int ptl = ck/24, rem = ck - ptl*24;
    int t = rem >> 3, c8 = rem & 7;
    int pt = pt0 + ptl;
    const float* up = uvi + (size_t)pt*9 + t*3;
    float u = up[0], v = up[1];
    int vid = (int)up[2];
    float xf = u*127.f, yf = v*127.f;
    int x0 = min(max((int)floorf(xf), 0), 126);
    int y0 = min(max((int)floorf(yf), 0), 126);
    float wx = xf - (float)x0, wy = yf - (float)y0;
    const short* cb = nts + ((size_t)((vid*128 + y0)*128 + x0))*64 + c8*8;
    s8v c00 = *(const s8v*)(cb);
    s8v c01 = *(const s8v*)(cb + 64);
    s8v c10 = *(const s8v*)(cb + 8192);
    s8v c11 = *(const s8v*)(cb + 8192 + 64);
    f4v o0, o1;
    s8v pk;
    #pragma unroll
    for (int e=0;e<8;e++){
      float a = b2f(c00[e]); a += wx*(b2f(c01[e]) - a);
      float b = b2f(c10[e]); b += wx*(b2f(c11[e]) - b);
      float val = a + wy*(b - a);
      if (e < 4) o0[e] = val; else o1[e-4] = val;
      pk[e] = f2bs(val);
    }
    float* op = outFeats + ((size_t)pt*3 + t)*64 + c8*8;
    *(f4v*)op = o0;
    *(f4v*)(op+4) = o1;
    *(s8v*)(&lds_fb[(ptl*3 + t)*72 + c8*8]) = pk;
  }

  __syncthreads();

  // ---- phase 2: attention. wave wid owns pts [wid*16, wid*16+16) ----
  const int ptl16 = wid*16 + p;
  const int pt = pt0 + ptl16;

  s8v fb[3][2];
  #pragma unroll
  for (int t=0;t<3;t++)
    #pragma unroll
    for (int kc=0;kc<2;kc++)
      fb[t][kc] = *(const s8v*)(&lds_fb[(ptl16*3 + t)*72 + kc*32 + g*8]);

  float rd0 = raydir[(size_t)pt*3+0];
  float rd1 = raydir[(size_t)pt*3+1];
  float rd2 = raydir[(size_t)pt*3+2];
  s8v xb[2];
  #pragma unroll
  for (int kc=0;kc<2;kc++){
    s8v tmp;
    #pragma unroll
    for (int e=0;e<8;e++){
      int j = kc*32 + g*8 + e;
      float hv = fmaxf(rb1[j] + rw1[j*3]*rd0 + rw1[j*3+1]*rd1 + rw1[j*3+2]*rd2, 0.f);
      tmp[e] = f2bs(hv);
    }
    xb[kc] = tmp;
  }

  // qh = wqr @ h + bqr
  f4v acc[4];
  #pragma unroll
  for (int m=0;m<4;m++) acc[m] = FZ;
  #pragma unroll
  for (int kc=0;kc<2;kc++){
    #pragma unroll
    for (int m=0;m<4;m++)
      acc[m] = __builtin_amdgcn_mfma_f32_16x16x32_bf16(AFRG(wqrb), xb[kc], acc[m], 0,0,0);
  }
  float qh[4][4];
  #pragma unroll
  for (int m=0;m<4;m++){
    f4v bb = *(const f4v*)(bqr + m*16 + g*4);
    #pragma unroll
    for (int r=0;r<4;r++) qh[m][r] = acc[m][r] + bb[r];
  }

  s8v wkf[2][4];
  #pragma unroll
  for (int kc=0;kc<2;kc++)
    #pragma unroll
    for (int m=0;m<4;m++)
      wkf[kc][m] = AFRG(wkb);

  float sc[3][4];
  #pragma unroll
  for (int t=0;t<3;t++){
    f4v ka[4];
    #pragma unroll
    for (int m=0;m<4;m++) ka[m] = FZ;
    #pragma unroll
    for (int kc=0;kc<2;kc++){
      #pragma unroll
      for (int m=0;m<4;m++)
        ka[m] = __builtin_amdgcn_mfma_f32_16x16x32_bf16(wkf[kc][m], fb[t][kc], ka[m], 0,0,0);
    }
    #pragma unroll
    for (int m=0;m<4;m++){
      f4v bb = *(const f4v*)(bk + m*16 + g*4);
      float part = 0.f;
      #pragma unroll
      for (int r=0;r<4;r++) part += qh[m][r]*(ka[m][r] + bb[r]);
      part += __shfl_xor(part, 16, 64);
      part += __shfl_xor(part, 32, 64);
      sc[t][m] = part*0.25f;
    }
  }

  #pragma unroll
  for (int m=0;m<4;m++){
    float mx = fmaxf(fmaxf(sc[0][m], sc[1][m]), sc[2][m]);
    float e0 = __expf(sc[0][m]-mx);
    float e1 = __expf(sc[1][m]-mx);
    float e2 = __expf(sc[2][m]-mx);
    float inv = 1.f/(e0+e1+e2);
    sc[0][m] = e0*inv; sc[1][m] = e1*inv; sc[2][m] = e2*inv;
  }

  s8v wvf[2][4];
  #pragma unroll
  for (int kc=0;kc<2;kc++)
    #pragma unroll
    for (int m=0;m<4;m++)
      wvf[kc][m] = AFRG(wvb);

  float o[4][4];
  #pragma unroll
  for (int m=0;m<4;m++)
    #pragma unroll
    for (int r=0;r<4;r++) o[m][r] = 0.f;
  #pragma unroll
  for (int t=0;t<3;t++){
    f4v va[4];
    #pragma unroll
    for (int m=0;m<4;m++) va[m] = FZ;
    #pragma unroll
    for (int kc=0;kc<2;kc++){
      #pragma unroll
      for (int m=0;m<4;m++)
        va[m] = __builtin_amdgcn_mfma_f32_16x16x32_bf16(wvf[kc][m], fb[t][kc], va[m], 0,0,0);
    }
    #pragma unroll
    for (int m=0;m<4;m++)
      #pragma unroll
      for (int r=0;r<4;r++) o[m][r] += sc[t][m]*va[m][r];
  }
  #pragma unroll
  for (int m=0;m<4;m++){
    f4v bb = *(const f4v*)(bv + m*16 + g*4);
    #pragma unroll
    for (int r=0;r<4;r++) o[m][r] += bb[r];
  }

  // relayout o (D-frag) -> B-frag via this wave's dead lds_fb region
  {
    unsigned* rl = (unsigned*)lds_fb + wid*1728;
    #pragma unroll
    for (int m=0;m<4;m++){
      unsigned lo = pk2(o[m][0], o[m][1]);
      unsigned hi = pk2(o[m][2], o[m][3]);
      rl[p*36 + m*8 + g*2] = lo;
      rl[p*36 + m*8 + g*2 + 1] = hi;
    }
    xb[0] = __builtin_bit_cast(s8v, *(uint4*)(rl + p*36 + g*4));
    xb[1] = __builtin_bit_cast(s8v, *(uint4*)(rl + p*36 + 16 + g*4));
  }

  // out = wo @ o + bo
  #pragma unroll
  for (int m=0;m<4;m++) acc[m] = FZ;
  #pragma unroll
  for (int kc=0;kc<2;kc++){
    #pragma unroll
    for (int m=0;m<4;m++)
      acc[m] = __builtin_amdgcn_mfma_f32_16x16x32_bf16(AFRG(wob), xb[kc], acc[m], 0,0,0);
  }
  #pragma unroll
  for (int m=0;m<4;m++){
    f4v bb = *(const f4v*)(bo + m*16 + g*4);
    f4v res;
    #pragma unroll
    for (int r=0;r<4;r++) res[r] = acc[m][r] + bb[r];
    *(f4v*)(outFused + (size_t)pt*64 + m*16 + g*4) = res;
  }
}

extern "C" void kernel_launch(void* const* d_in, const int* in_sizes, int n_in,
                              void* d_out, int out_size, void* d_ws, size_t ws_size,
                              hipStream_t stream)
{
  const float* view_tex = (const float*)d_in[0];
  const float* uvi    = (const float*)d_in[1];
  const float* raydir = (const float*)d_in[2];
  const float* w1 = (const float*)d_in[3];
  const float* b1 = (const float*)d_in[4];
  const float* w2 = (const float*)d_in[5];
  const float* b2 = (const float*)d_in[6];
  const float* w3 = (const float*)d_in[7];
  const float* b3 = (const float*)d_in[8];
  const float* rw1 = (const float*)d_in[9];
  const float* rb1 = (const float*)d_in[10];
  const float* rw2 = (const float*)d_in[11];
  const float* rb2 = (const float*)d_in[12];
  const float* wq = (const float*)d_in[13];
  const float* bq = (const float*)d_in[14];
  const float* wk = (const float*)d_in[15];
  const float* bk = (const float*)d_in[16];
  const float* wv = (const float*)d_in[17];
  const float* bv = (const float*)d_in[18];
  const float* wo = (const float*)d_in[19];
  const float* bo = (const float*)d_in[20];
  float* out = (float*)d_out;

  const int V = in_sizes[0] / (3*512*512);     // 8
  const int B = in_sizes[1] / 9;               // 262144
  const size_t FEATS_OFF = (size_t)B*64;

  const size_t C2F  = (size_t)V*256*256*64*2;
  const size_t C2V  = (size_t)256*256*64*2;
  const size_t NTSB = (size_t)V*128*128*64*2;
  const size_t WREG = 262144;

  char* base = (char*)d_ws;
  bool full = (ws_size >= C2F + NTSB + WREG);

  char *c2, *ntsp, *wreg;
  if (full){
    c2 = base; ntsp = c2 + C2F; wreg = ntsp + NTSB;
  } else {
    c2 = base; ntsp = c2 + C2V; wreg = ntsp + NTSB;
  }
  short* w1b = (short*)(wreg);
  short* w2b = (short*)(wreg + 3456);
  short* w3b = (short*)(wreg + 40320);
  short* wqrb = (short*)(wreg + 122240);
  short* wkb  = (short*)(wreg + 130432);
  short* wvb  = (short*)(wreg + 138624);
  short* wob  = (short*)(wreg + 146816);
  float* bqr  = (float*)(wreg + 155008);

  k0_prep<<<dim3(300),256,0,stream>>>(w1,w2,w3,rw2,wq,wk,wv,wo,wreg);
  k0b_fold<<<dim3(1),256,0,stream>>>(wq, rw2, rb2, bq, wreg);

  if (full){
    kc12<<<dim3(4,128,V),256,0,stream>>>(view_tex,(short*)c2,w1b,b1,w2b,b2,0);
    conv_mfma_ms<64,2><<<dim3(2,128,V),256,0,stream>>>((const short*)c2,(short*)ntsp,w3b,b3,256,256,128,0);
  } else {
    for (int v=0; v<V; v++){
      kc12<<<dim3(4,128,1),256,0,stream>>>(view_tex,(short*)c2,w1b,b1,w2b,b2,v);
      conv_mfma_ms<64,2><<<dim3(2,128,1),256,0,stream>>>((const short*)c2,(short*)ntsp,w3b,b3,256,256,128,v);
    }
  }

  k45_fused<<<dim3(B/64),256,0,stream>>>((const short*)ntsp, uvi, raydir,
      rw1, rb1, wqrb, bqr, wkb, bk, wvb, bv, wob, bo,
      out, out + FEATS_OFF);
}

// Round 19
// 308.003 us; speedup vs baseline: 1.3713x; 1.0435x over previous
//
#include <hip/hip_runtime.h>

typedef short s8v __attribute__((ext_vector_type(8)));
typedef short s4v __attribute__((ext_vector_type(4)));
typedef float f4v __attribute__((ext_vector_type(4)));

#define DEV __device__ __forceinline__

DEV short f2bs(float f){
  unsigned int u = __float_as_uint(f);
  u += 0x7fffu + ((u >> 16) & 1u);
  return (short)(u >> 16);
}
DEV float b2f(short s){
  return __uint_as_float(((unsigned int)(unsigned short)s) << 16);
}
DEV float lrelu(float x){ return x >= 0.f ? x : 0.01f*x; }
DEV unsigned pk2(float a, float b){
  return (unsigned)(unsigned short)f2bs(a) | ((unsigned)(unsigned short)f2bs(b) << 16);
}

// ---------------- K0: weight prep ----------------
__global__ __launch_bounds__(256) void k0_prep(
    const float* __restrict__ w1, const float* __restrict__ w2,
    const float* __restrict__ w3, const float* __restrict__ rw2,
    const float* __restrict__ wq, const float* __restrict__ wk,
    const float* __restrict__ wv, const float* __restrict__ wo,
    char* __restrict__ wreg)
{
  int idx = blockIdx.x*256 + threadIdx.x;
  short* w1b = (short*)(wreg);
  short* w2b = (short*)(wreg + 3456);
  short* w3b = (short*)(wreg + 40320);
  short* rw2b = (short*)(wreg + 114048);
  short* wkb  = (short*)(wreg + 130432);
  short* wvb  = (short*)(wreg + 138624);
  short* wob  = (short*)(wreg + 146816);
  if (idx < 1024){
    int e = idx & 7, l = (idx >> 3) & 63, m = idx >> 9;
    int k = (l >> 4)*8 + e;
    int cout = m*16 + (l & 15);
    w1b[idx] = (k < 27) ? f2bs(w1[cout*27 + k]) : (short)0;
  } else if (idx < 19456){
    int j = idx - 1024;
    int kk = j / 2048, c = (j >> 5) & 63, ci = j & 31;
    w2b[j] = f2bs(w2[c*288 + ci*9 + kk]);
  } else if (idx < 56320){
    int j = idx - 19456;
    int kk = j / 4096, c = (j >> 6) & 63, ci = j & 63;
    w3b[j] = f2bs(w3[c*576 + ci*9 + kk]);
  } else if (idx < 60416){
    int j = idx - 56320; rw2b[j] = f2bs(rw2[j]);
  } else if (idx < 64512){
    // wqrb written by k0b
  } else if (idx < 68608){
    int j = idx - 64512; wkb[j] = f2bs(wk[j]);
  } else if (idx < 72704){
    int j = idx - 68608; wvb[j] = f2bs(wv[j]);
  } else if (idx < 76800){
    int j = idx - 72704; wob[j] = f2bs(wo[j]);
  }
}

// ---------------- K0b: fold wq*rw2 -> wqrb (bf16), wq@rb2+bq -> bqr (f32) ----------------
__global__ __launch_bounds__(256) void k0b_fold(
    const float* __restrict__ wq, const float* __restrict__ rw2,
    const float* __restrict__ rb2, const float* __restrict__ bq,
    char* __restrict__ wreg)
{
  short* wqrb = (short*)(wreg + 122240);
  float* bqr  = (float*)(wreg + 155008);
  int tid = threadIdx.x;
  int i = tid >> 2, k0 = (tid & 3)*16;
  #pragma unroll
  for (int kk=0; kk<16; kk++){
    int k = k0 + kk;
    float s = 0.f;
    #pragma unroll
    for (int j=0; j<64; j++) s += wq[i*64+j]*rw2[j*64+k];
    wqrb[i*64+k] = f2bs(s);
  }
  if (tid < 64){
    float s = bq[tid];
    #pragma unroll
    for (int j=0; j<64; j++) s += wq[tid*64+j]*rb2[j];
    bqr[tid] = s;
  }
}

// ---------------- KC12: fused conv1+conv2, XCD-aware row swizzle ----------------
__global__ __launch_bounds__(256) void kc12(
    const float* __restrict__ vt, short* __restrict__ c2,
    const short* __restrict__ w1b, const float* __restrict__ b1,
    const short* __restrict__ w2b, const float* __restrict__ b2, int v0)
{
  __shared__ short srcT[3108];
  __shared__ short rb[4][2880];
  const int tid = threadIdx.x;
  const int l = tid & 63, wid = tid >> 6;
  const int p = l & 15, g = l >> 4;
  // XCD swizzle: blocks y and y+8 share an XCD (flat%8); give them consecutive rows.
  const int yb = blockIdx.y;
  const int oyb = (yb & 7)*16 + (yb >> 3);
  const int OXB = blockIdx.x*64, OYB = oyb*2;
  const float* src = vt + (size_t)(v0 + blockIdx.z)*3*512*512;

  #pragma unroll
  for (int it=0; it<13; it++){
    int idx = it*256 + tid;
    if (idx < 3108){
      int ci = idx/1036, rem = idx - ci*1036;
      int row = rem/148, col = rem - row*148;
      int gr = min(max(2*OYB - 2 + row, 0), 511);
      int gc = min(max(2*OXB - 2 + col, 0), 511);
      srcT[idx] = f2bs(src[((size_t)ci*512 + gr)*512 + gc]);
    }
  }

  int boffB[8];
  #pragma unroll
  for (int e=0;e<8;e++){
    int k = g*8 + e;
    int ci = (k*57) >> 9;
    int r9 = k - ci*9;
    int dy = (r9*11) >> 5;
    int dx = r9 - dy*3;
    boffB[e] = (k < 27) ? (ci*1036 + dy*148 + dx) : 0;
  }
  s8v af0 = *(const s8v*)(w1b + l*8);
  s8v af1 = *(const s8v*)(w1b + 512 + l*8);
  f4v cb0 = *(const f4v*)(b1 + g*4);
  f4v cb1 = *(const f4v*)(b1 + 16 + g*4);

  const int dlt = wid >> 1, h = wid & 1;
  const int oy = OYB + dlt;
  const int ox0 = OXB + h*32;
  const int Cw0 = 2*ox0 - 1;
  short* myrb = rb[wid];
  const f4v FZ = {0.f,0.f,0.f,0.f};
  f4v acc[2][4];
  #pragma unroll
  for (int s2=0;s2<2;s2++)
    #pragma unroll
    for (int m=0;m<4;m++) acc[s2][m] = FZ;

  __syncthreads();

  #pragma unroll
  for (int ky=0; ky<3; ky++){
    const int R = min(max(2*oy + ky - 1, 0), 511);
    const int trb = R - 2*OYB + 1;
    const int sbase = trb*148 + 64*h + p;

    #pragma unroll
    for (int s=0; s<5; s++){
      s8v bf;
      #pragma unroll
      for (int e=0;e<8;e++) bf[e] = srcT[boffB[e] + sbase + s*16];
      f4v d0 = __builtin_amdgcn_mfma_f32_16x16x32_bf16(af0, bf, FZ, 0,0,0);
      f4v d1 = __builtin_amdgcn_mfma_f32_16x16x32_bf16(af1, bf, FZ, 0,0,0);
      int wcol = s*16 + p;
      uint2 wa = { pk2(lrelu(d0[0]+cb0[0]), lrelu(d0[1]+cb0[1])),
                   pk2(lrelu(d0[2]+cb0[2]), lrelu(d0[3]+cb0[3])) };
      *(uint2*)(myrb + wcol*36 + g*4) = wa;
      uint2 wb2 = { pk2(lrelu(d1[0]+cb1[0]), lrelu(d1[1]+cb1[1])),
                    pk2(lrelu(d1[2]+cb1[2]), lrelu(d1[3]+cb1[3])) };
      *(uint2*)(myrb + wcol*36 + 16 + g*4) = wb2;
    }

    #pragma unroll
    for (int s2=0; s2<2; s2++){
      const int locox = s2*16 + p;
      #pragma unroll
      for (int kx=0; kx<3; kx++){
        int raw = Cw0 + 2*locox + kx;
        int ri = max(raw, 0) - Cw0;
        uint2 lo2 = *(const uint2*)(myrb + ri*36 + g*8);
        uint2 hi2 = *(const uint2*)(myrb + ri*36 + g*8 + 4);
        uint4 t4 = {lo2.x, lo2.y, hi2.x, hi2.y};
        s8v bf2 = __builtin_bit_cast(s8v, t4);
        #pragma unroll
        for (int m=0;m<4;m++){
          s8v afr = *(const s8v*)(w2b + ((ky*3+kx)*64 + m*16 + p)*32 + g*8);
          acc[s2][m] = __builtin_amdgcn_mfma_f32_16x16x32_bf16(afr, bf2, acc[s2][m], 0,0,0);
        }
      }
    }
  }

  #pragma unroll
  for (int s2=0; s2<2; s2++){
    short* o = c2 + (((size_t)blockIdx.z*256 + oy)*256 + ox0 + s2*16 + p)*64;
    #pragma unroll
    for (int m=0;m<4;m++){
      f4v bb = *(const f4v*)(b2 + m*16 + g*4);
      s4v pk;
      #pragma unroll
      for (int r=0;r<4;r++) pk[r] = f2bs(lrelu(acc[s2][m][r] + bb[r]));
      *(s4v*)(o + m*16 + g*4) = pk;
    }
  }
}

// ---------------- conv3: implicit-GEMM MFMA, stride 2, XCD-aware row swizzle ----------------
template<int CIN, int TILES>
__global__ __launch_bounds__(256) void conv_mfma(
    const short* __restrict__ src0, short* __restrict__ dst,
    const short* __restrict__ wb, const float* __restrict__ bias,
    int IH, int IW, int OW, int dstV0)
{
  const int l = threadIdx.x & 63, w = threadIdx.x >> 6;
  const int p = l & 15, g = l >> 4;
  const int ox0 = blockIdx.x*(64*TILES) + w*(16*TILES) + p;
  const int yb = blockIdx.y;
  const int oy = (yb & 7)*16 + (yb >> 3);     // XCD swizzle (gridDim.y==128)
  const short* src = src0 + (size_t)blockIdx.z*IH*IW*CIN;
  const f4v FZ = {0.f,0.f,0.f,0.f};
  f4v acc[TILES][4];
  #pragma unroll
  for (int tl=0;tl<TILES;tl++)
    #pragma unroll
    for (int m=0;m<4;m++) acc[tl][m] = FZ;
  #pragma unroll
  for (int ky=0;ky<3;ky++){
    int iy = min(max(2*oy+ky-1, 0), IH-1);
    #pragma unroll
    for (int kx=0;kx<3;kx++){
      #pragma unroll
      for (int ch=0; ch<CIN/32; ch++){
        s8v bfrag[TILES];
        #pragma unroll
        for (int tl=0;tl<TILES;tl++){
          int ix = min(max(2*(ox0 + 16*tl)+kx-1, 0), IW-1);
          bfrag[tl] = *(const s8v*)(src + ((size_t)iy*IW + ix)*CIN + ch*32 + g*8);
        }
        #pragma unroll
        for (int m=0;m<4;m++){
          s8v afrag = *(const s8v*)(wb + ((ky*3+kx)*64 + m*16 + p)*CIN + ch*32 + g*8);
          #pragma unroll
          for (int tl=0;tl<TILES;tl++)
            acc[tl][m] = __builtin_amdgcn_mfma_f32_16x16x32_bf16(afrag, bfrag[tl], acc[tl][m], 0,0,0);
        }
      }
    }
  }
  const int OH = gridDim.y;
  #pragma unroll
  for (int tl=0;tl<TILES;tl++){
    short* o = dst + (((size_t)(dstV0 + blockIdx.z)*OH + oy)*OW + ox0 + 16*tl)*64;
    #pragma unroll
    for (int m=0;m<4;m++){
      f4v bb = *(const f4v*)(bias + m*16 + g*4);
      s4v pk;
      #pragma unroll
      for (int r=0;r<4;r++) pk[r] = f2bs(lrelu(acc[tl][m][r] + bb[r]));
      *(s4v*)(o + m*16 + g*4) = pk;
    }
  }
}

// ---------------- K45: fused gather + rayMLP + MHA (R11 structure, best measured) ----------------
#define AFRG(W) (*(const s8v*)((W) + (m*16 + p)*64 + kc*32 + g*8))

__global__ __launch_bounds__(256) void k45_fused(
    const short* __restrict__ nts, const float* __restrict__ uvi,
    const float* __restrict__ raydir,
    const float* __restrict__ rw1, const float* __restrict__ rb1,
    const short* __restrict__ wqrb, const float* __restrict__ bqr,
    const short* __restrict__ wkb, const float* __restrict__ bk,
    const short* __restrict__ wvb, const float* __restrict__ bv,
    const short* __restrict__ wob, const float* __restrict__ bo,
    float* __restrict__ outFused, float* __restrict__ outFeats)
{
  __shared__ short lds_fb[64*3*72];           // 27648 B
  const int tid = threadIdx.x;
  const int l = tid & 63, wid = tid >> 6;
  const int p = l & 15, g = l >> 4;
  const int pt0 = blockIdx.x*64;
  const f4v FZ = {0.f,0.f,0.f,0.f};

  // ---- phase 1: gather 64 pts x 3 tok x 64 ch (8-ch chunks) ----
  #pragma unroll
  for (int i=0; i<6; i++){
    int ck = i*256 + tid;                     // [0,1536)
    int ptl = ck/24, rem = ck - ptl*24;
    int t = rem >> 3, c8 = rem & 7;
    int pt = pt0 + ptl;
    const float* up = uvi + (size_t)pt*9 + t*3;
    float u = up[0], v = up[1];
    int vid = (int)up[2];
    float xf = u*127.f, yf = v*127.f;
    int x0 = min(max((int)floorf(xf), 0), 126);
    int y0 = min(max((int)floorf(yf), 0), 126);
    float wx = xf - (float)x0, wy = yf - (float)y0;
    const short* cb = nts + ((size_t)((vid*128 + y0)*128 + x0))*64 + c8*8;
    s8v c00 = *(const s8v*)(cb);
    s8v c01 = *(const s8v*)(cb + 64);
    s8v c10 = *(const s8v*)(cb + 8192);
    s8v c11 = *(const s8v*)(cb + 8192 + 64);
    f4v o0, o1;
    s8v pk;
    #pragma unroll
    for (int e=0;e<8;e++){
      float a = b2f(c00[e]); a += wx*(b2f(c01[e]) - a);
      float b = b2f(c10[e]); b += wx*(b2f(c11[e]) - b);
      float val = a + wy*(b - a);
      if (e < 4) o0[e] = val; else o1[e-4] = val;
      pk[e] = f2bs(val);
    }
    float* op = outFeats + ((size_t)pt*3 + t)*64 + c8*8;
    *(f4v*)op = o0;
    *(f4v*)(op+4) = o1;
    *(s8v*)(&lds_fb[(ptl*3 + t)*72 + c8*8]) = pk;
  }

  __syncthreads();

  // ---- phase 2: attention. wave wid owns pts [wid*16, wid*16+16) ----
  const int ptl16 = wid*16 + p;
  const int pt = pt0 + ptl16;

  s8v fb[3][2];
  #pragma unroll
  for (int t=0;t<3;t++)
    #pragma unroll
    for (int kc=0;kc<2;kc++)
      fb[t][kc] = *(const s8v*)(&lds_fb[(ptl16*3 + t)*72 + kc*32 + g*8]);

  float rd0 = raydir[(size_t)pt*3+0];
  float rd1 = raydir[(size_t)pt*3+1];
  float rd2 = raydir[(size_t)pt*3+2];
  s8v xb[2];
  #pragma unroll
  for (int kc=0;kc<2;kc++){
    s8v tmp;
    #pragma unroll
    for (int e=0;e<8;e++){
      int j = kc*32 + g*8 + e;
      float hv = fmaxf(rb1[j] + rw1[j*3]*rd0 + rw1[j*3+1]*rd1 + rw1[j*3+2]*rd2, 0.f);
      tmp[e] = f2bs(hv);
    }
    xb[kc] = tmp;
  }

  // qh = wqr @ h + bqr
  f4v acc[4];
  #pragma unroll
  for (int m=0;m<4;m++) acc[m] = FZ;
  #pragma unroll
  for (int kc=0;kc<2;kc++){
    #pragma unroll
    for (int m=0;m<4;m++)
      acc[m] = __builtin_amdgcn_mfma_f32_16x16x32_bf16(AFRG(wqrb), xb[kc], acc[m], 0,0,0);
  }
  float qh[4][4];
  #pragma unroll
  for (int m=0;m<4;m++){
    f4v bb = *(const f4v*)(bqr + m*16 + g*4);
    #pragma unroll
    for (int r=0;r<4;r++) qh[m][r] = acc[m][r] + bb[r];
  }

  s8v wkf[2][4];
  #pragma unroll
  for (int kc=0;kc<2;kc++)
    #pragma unroll
    for (int m=0;m<4;m++)
      wkf[kc][m] = AFRG(wkb);

  float sc[3][4];
  #pragma unroll
  for (int t=0;t<3;t++){
    f4v ka[4];
    #pragma unroll
    for (int m=0;m<4;m++) ka[m] = FZ;
    #pragma unroll
    for (int kc=0;kc<2;kc++){
      #pragma unroll
      for (int m=0;m<4;m++)
        ka[m] = __builtin_amdgcn_mfma_f32_16x16x32_bf16(wkf[kc][m], fb[t][kc], ka[m], 0,0,0);
    }
    #pragma unroll
    for (int m=0;m<4;m++){
      f4v bb = *(const f4v*)(bk + m*16 + g*4);
      float part = 0.f;
      #pragma unroll
      for (int r=0;r<4;r++) part += qh[m][r]*(ka[m][r] + bb[r]);
      part += __shfl_xor(part, 16, 64);
      part += __shfl_xor(part, 32, 64);
      sc[t][m] = part*0.25f;
    }
  }

  #pragma unroll
  for (int m=0;m<4;m++){
    float mx = fmaxf(fmaxf(sc[0][m], sc[1][m]), sc[2][m]);
    float e0 = __expf(sc[0][m]-mx);
    float e1 = __expf(sc[1][m]-mx);
    float e2 = __expf(sc[2][m]-mx);
    float inv = 1.f/(e0+e1+e2);
    sc[0][m] = e0*inv; sc[1][m] = e1*inv; sc[2][m] = e2*inv;
  }

  s8v wvf[2][4];
  #pragma unroll
  for (int kc=0;kc<2;kc++)
    #pragma unroll
    for (int m=0;m<4;m++)
      wvf[kc][m] = AFRG(wvb);

  float o[4][4];
  #pragma unroll
  for (int m=0;m<4;m++)
    #pragma unroll
    for (int r=0;r<4;r++) o[m][r] = 0.f;
  #pragma unroll
  for (int t=0;t<3;t++){
    f4v va[4];
    #pragma unroll
    for (int m=0;m<4;m++) va[m] = FZ;
    #pragma unroll
    for (int kc=0;kc<2;kc++){
      #pragma unroll
      for (int m=0;m<4;m++)
        va[m] = __builtin_amdgcn_mfma_f32_16x16x32_bf16(wvf[kc][m], fb[t][kc], va[m], 0,0,0);
    }
    #pragma unroll
    for (int m=0;m<4;m++)
      #pragma unroll
      for (int r=0;r<4;r++) o[m][r] += sc[t][m]*va[m][r];
  }
  #pragma unroll
  for (int m=0;m<4;m++){
    f4v bb = *(const f4v*)(bv + m*16 + g*4);
    #pragma unroll
    for (int r=0;r<4;r++) o[m][r] += bb[r];
  }

  // relayout o (D-frag) -> B-frag via this wave's dead lds_fb region
  {
    unsigned* rl = (unsigned*)lds_fb + wid*1728;
    #pragma unroll
    for (int m=0;m<4;m++){
      unsigned lo = pk2(o[m][0], o[m][1]);
      unsigned hi = pk2(o[m][2], o[m][3]);
      rl[p*36 + m*8 + g*2] = lo;
      rl[p*36 + m*8 + g*2 + 1] = hi;
    }
    xb[0] = __builtin_bit_cast(s8v, *(uint4*)(rl + p*36 + g*4));
    xb[1] = __builtin_bit_cast(s8v, *(uint4*)(rl + p*36 + 16 + g*4));
  }

  // out = wo @ o + bo
  #pragma unroll
  for (int m=0;m<4;m++) acc[m] = FZ;
  #pragma unroll
  for (int kc=0;kc<2;kc++){
    #pragma unroll
    for (int m=0;m<4;m++)
      acc[m] = __builtin_amdgcn_mfma_f32_16x16x32_bf16(AFRG(wob), xb[kc], acc[m], 0,0,0);
  }
  #pragma unroll
  for (int m=0;m<4;m++){
    f4v bb = *(const f4v*)(bo + m*16 + g*4);
    f4v res;
    #pragma unroll
    for (int r=0;r<4;r++) res[r] = acc[m][r] + bb[r];
    *(f4v*)(outFused + (size_t)pt*64 + m*16 + g*4) = res;
  }
}

extern "C" void kernel_launch(void* const* d_in, const int* in_sizes, int n_in,
                              void* d_out, int out_size, void* d_ws, size_t ws_size,
                              hipStream_t stream)
{
  const float* view_tex = (const float*)d_in[0];
  const float* uvi    = (const float*)d_in[1];
  const float* raydir = (const float*)d_in[2];
  const float* w1 = (const float*)d_in[3];
  const float* b1 = (const float*)d_in[4];
  const float* w2 = (const float*)d_in[5];
  const float* b2 = (const float*)d_in[6];
  const float* w3 = (const float*)d_in[7];
  const float* b3 = (const float*)d_in[8];
  const float* rw1 = (const float*)d_in[9];
  const float* rb1 = (const float*)d_in[10];
  const float* rw2 = (const float*)d_in[11];
  const float* rb2 = (const float*)d_in[12];
  const float* wq = (const float*)d_in[13];
  const float* bq = (const float*)d_in[14];
  const float* wk = (const float*)d_in[15];
  const float* bk = (const float*)d_in[16];
  const float* wv = (const float*)d_in[17];
  const float* bv = (const float*)d_in[18];
  const float* wo = (const float*)d_in[19];
  const float* bo = (const float*)d_in[20];
  float* out = (float*)d_out;

  const int V = in_sizes[0] / (3*512*512);     // 8
  const int B = in_sizes[1] / 9;               // 262144
  const size_t FEATS_OFF = (size_t)B*64;

  const size_t C2F  = (size_t)V*256*256*64*2;
  const size_t C2V  = (size_t)256*256*64*2;
  const size_t NTSB = (size_t)V*128*128*64*2;
  const size_t WREG = 262144;

  char* base = (char*)d_ws;
  bool full = (ws_size >= C2F + NTSB + WREG);

  char *c2, *ntsp, *wreg;
  if (full){
    c2 = base; ntsp = c2 + C2F; wreg = ntsp + NTSB;
  } else {
    c2 = base; ntsp = c2 + C2V; wreg = ntsp + NTSB;
  }
  short* w1b = (short*)(wreg);
  short* w2b = (short*)(wreg + 3456);
  short* w3b = (short*)(wreg + 40320);
  short* wqrb = (short*)(wreg + 122240);
  short* wkb  = (short*)(wreg + 130432);
  short* wvb  = (short*)(wreg + 138624);
  short* wob  = (short*)(wreg + 146816);
  float* bqr  = (float*)(wreg + 155008);

  k0_prep<<<dim3(300),256,0,stream>>>(w1,w2,w3,rw2,wq,wk,wv,wo,wreg);
  k0b_fold<<<dim3(1),256,0,stream>>>(wq, rw2, rb2, bq, wreg);

  if (full){
    kc12<<<dim3(4,128,V),256,0,stream>>>(view_tex,(short*)c2,w1b,b1,w2b,b2,0);
    conv_mfma<64,2><<<dim3(1,128,V),256,0,stream>>>((const short*)c2,(short*)ntsp,w3b,b3,256,256,128,0);
  } else {
    for (int v=0; v<V; v++){
      kc12<<<dim3(4,128,1),256,0,stream>>>(view_tex,(short*)c2,w1b,b1,w2b,b2,v);
      conv_mfma<64,2><<<dim3(1,128,1),256,0,stream>>>((const short*)c2,(short*)ntsp,w3b,b3,256,256,128,v);
    }
  }

  k45_fused<<<dim3(B/64),256,0,stream>>>((const short*)ntsp, uvi, raydir,
      rw1, rb1, wqrb, bqr, wkb, bk, wvb, bv, wob, bo,
      out, out + FEATS_OFF);
}